// Round 1
// baseline (1731.196 us; speedup 1.0000x reference)
//
#include <hip/hip_runtime.h>
#include <stdint.h>

// ---------------------------------------------------------------------------
// ST-LSTM on MI355X.
//  K0 k_prep   : build W_catT (2048x1536 bf16, transposed+XOR-swizzled),
//                Wh_rearr (2048x512 bf16, col-reordered per recurrence block,
//                swizzled), zero h ping-pong buffers + barrier state.
//  K1 k_gather : A_cat (16384x1536 bf16, swizzled) = [x | q/3600 | sp/1000],
//                q/sp masked to 0 at t==0.
//  K2 k_gemm   : G (T,B,4H) bf16 = A_cat @ W_cat + bi   (m97-style 128^2 tile,
//                global_load_lds(16), 16x16x32 bf16 MFMA, swizzled LDS reads)
//  K3 k_recur  : 64 persistent blocks (4 batch-groups x 16 col-groups),
//                Wh slice resident in LDS, per-step: h stage (agent atomics),
//                MFMA h@Wh_slice, gates, outputs, grid barrier (agent atomics,
//                monotonic slots, no L2 fences needed: all cross-block data
//                moves via agent-scope atomics = coherent at Infinity Cache).
//
// ws layout (bytes), total need = 125,964,288 (~120.1 MiB):
#define A_CAT_OFF  0ull                  // 16384*3072
#define WCT_OFF    50331648ull           // 2048*3072
#define WHR_OFF    56623104ull           // 2048*1024
#define G_OFF      58720256ull           // 16384*2048*2
#define HBUF_OFF   125829120ull          // 2 * 16384 u32 (64x512 bf16 x2)
#define BAR_OFF    125960192ull          // slots[64] @+0, gen @+1024, 4KB
#define WS_NEED    125964288ull

typedef short bf16x8 __attribute__((ext_vector_type(8)));
typedef float f32x4  __attribute__((ext_vector_type(4)));

__device__ __forceinline__ unsigned short f2bf(float f) {
  union { float f; uint32_t u; } v; v.f = f;
  uint32_t u = v.u;
  u += 0x7FFFu + ((u >> 16) & 1u);   // RNE
  return (unsigned short)(u >> 16);
}
__device__ __forceinline__ float bf2f(unsigned short h) {
  union { uint32_t u; float f; } v; v.u = ((uint32_t)h) << 16;
  return v.f;
}
__device__ __forceinline__ float fsigmoid(float x) { return 1.0f / (1.0f + __expf(-x)); }
__device__ __forceinline__ float ftanh(float x) {
  float e = __expf(2.0f * x);
  return 1.0f - 2.0f / (e + 1.0f);
}
__device__ __forceinline__ uint4 pack8(const unsigned short* v) {
  uint4 r;
  r.x = (uint32_t)v[0] | ((uint32_t)v[1] << 16);
  r.y = (uint32_t)v[2] | ((uint32_t)v[3] << 16);
  r.z = (uint32_t)v[4] | ((uint32_t)v[5] << 16);
  r.w = (uint32_t)v[6] | ((uint32_t)v[7] << 16);
  return r;
}

#define GLOAD_LDS16(GP, LP)                                                   \
  __builtin_amdgcn_global_load_lds(                                          \
      (const __attribute__((address_space(1))) uint32_t*)(GP),               \
      (__attribute__((address_space(3))) uint32_t*)(LP), 16, 0, 0)

// ---------------------------------------------------------------------- K0
__global__ __launch_bounds__(256) void k_prep(
    const float* __restrict__ Wi, const float* __restrict__ Wt,
    const float* __restrict__ Ws, const float* __restrict__ Wh,
    uint8_t* ws) {
  int id = blockIdx.x * 256 + threadIdx.x;
  if (id < 393216) {                       // W_catT: 2048 cols x 192 k-chunks
    int n  = id & 2047;
    int k0 = (id >> 11) << 3;
    unsigned short v[8];
#pragma unroll
    for (int j = 0; j < 8; ++j) {
      int k = k0 + j;
      float x;
      if (k < 512)       x = Wi[k * 2048 + n];
      else if (k < 1024) x = (n < 1536) ? Wt[(k - 512) * 1536 + n] : 0.0f;
      else               x = (n < 1536) ? Ws[(k - 1024) * 1536 + n] : 0.0f;
      v[j] = f2bf(x);
    }
    size_t off = WCT_OFF + (size_t)n * 3072 +
                 (size_t)(((uint32_t)k0 * 2u) ^ (((uint32_t)n & 7u) << 4));
    *(uint4*)(ws + off) = pack8(v);
  } else if (id < 524288) {                // Wh_rearr: 2048 cc x 64 k-chunks
    int id2 = id - 393216;
    int cc  = id2 & 2047;
    int k0  = (id2 >> 11) << 3;
    int col = ((cc >> 5) & 3) * 512 + (cc >> 7) * 32 + (cc & 31);
    unsigned short v[8];
#pragma unroll
    for (int j = 0; j < 8; ++j) v[j] = f2bf(Wh[(size_t)(k0 + j) * 2048 + col]);
    size_t off = WHR_OFF + (size_t)cc * 1024 +
                 (size_t)(((uint32_t)k0 * 2u) ^ (((uint32_t)cc & 7u) << 4));
    *(uint4*)(ws + off) = pack8(v);
  } else if (id < 532480) {                // zero h ping-pong
    uint4 z; z.x = z.y = z.z = z.w = 0u;
    *(uint4*)(ws + HBUF_OFF + (size_t)(id - 524288) * 16) = z;
  } else {                                 // zero barrier state (id < 532736)
    uint4 z; z.x = z.y = z.z = z.w = 0u;
    *(uint4*)(ws + BAR_OFF + (size_t)(id - 532480) * 16) = z;
  }
}

// ---------------------------------------------------------------------- K1
__global__ __launch_bounds__(192) void k_gather(
    const int* __restrict__ loc, const int* __restrict__ tdu,
    const int* __restrict__ tdl, const int* __restrict__ sdu,
    const int* __restrict__ sdl,
    const float* __restrict__ loc_emb, const float* __restrict__ tup,
    const float* __restrict__ tlo, const float* __restrict__ sup,
    const float* __restrict__ slo, uint8_t* ws) {
  int m  = blockIdx.x;        // row = b*256 + t
  int t  = m & 255;
  int k0 = threadIdx.x << 3;  // 192 chunks of 8
  float vals[8];
  if (k0 < 512) {
    const float* s = loc_emb + (size_t)loc[m] * 512 + k0;
#pragma unroll
    for (int j = 0; j < 8; ++j) vals[j] = s[j];
  } else if (k0 < 1024) {
    int e = k0 - 512;
    const float* a = tup + (size_t)tdu[m] * 512 + e;
    const float* b = tlo + (size_t)tdl[m] * 512 + e;
    float sc = (t > 0) ? (1.0f / 3600.0f) : 0.0f;
#pragma unroll
    for (int j = 0; j < 8; ++j) vals[j] = (a[j] + b[j]) * sc;
  } else {
    int e = k0 - 1024;
    const float* a = sup + (size_t)sdu[m] * 512 + e;
    const float* b = slo + (size_t)sdl[m] * 512 + e;
    float sc = (t > 0) ? (1.0f / 1000.0f) : 0.0f;
#pragma unroll
    for (int j = 0; j < 8; ++j) vals[j] = (a[j] + b[j]) * sc;
  }
  unsigned short v[8];
#pragma unroll
  for (int j = 0; j < 8; ++j) v[j] = f2bf(vals[j]);
  size_t off = A_CAT_OFF + (size_t)m * 3072 +
               (size_t)(((uint32_t)k0 * 2u) ^ (((uint32_t)m & 7u) << 4));
  *(uint4*)(ws + off) = pack8(v);
}

// ---------------------------------------------------------------------- K2
__global__ __launch_bounds__(256) void k_gemm(uint8_t* ws,
                                              const float* __restrict__ bi) {
  __shared__ uint8_t A_lds[16384];   // 128 rows x 64 k bf16 (swizzled content)
  __shared__ uint8_t B_lds[16384];   // 128 cols x 64 k bf16
  const uint8_t* Acat = ws + A_CAT_OFF;
  const uint8_t* Wct  = ws + WCT_OFF;
  uint8_t* Gp = ws + G_OFF;
  int tid = threadIdx.x;
  int lane = tid & 63, wave = tid >> 6;
  int wm = wave >> 1, wn = wave & 1;
  int tile_m = blockIdx.x >> 4, tile_n = blockIdx.x & 15;

  f32x4 acc[4][4];
#pragma unroll
  for (int m = 0; m < 4; ++m)
#pragma unroll
    for (int n = 0; n < 4; ++n) acc[m][n] = f32x4{0.f, 0.f, 0.f, 0.f};

  for (int kb = 0; kb < 1536; kb += 64) {
#pragma unroll
    for (int i = 0; i < 4; ++i) {
      int lidx = i * 256 + tid;
      int row = lidx >> 3, ch = lidx & 7;
      GLOAD_LDS16(Acat + (size_t)(tile_m * 128 + row) * 3072 + kb * 2 + ch * 16,
                  A_lds + (i * 256 + wave * 64) * 16);
    }
#pragma unroll
    for (int i = 0; i < 4; ++i) {
      int lidx = i * 256 + tid;
      int row = lidx >> 3, ch = lidx & 7;
      GLOAD_LDS16(Wct + (size_t)(tile_n * 128 + row) * 3072 + kb * 2 + ch * 16,
                  B_lds + (i * 256 + wave * 64) * 16);
    }
    __syncthreads();
#pragma unroll
    for (int kk = 0; kk < 2; ++kk) {
      int koff = kk * 64 + ((lane >> 4) << 4);
      bf16x8 af[4], bfr[4];
#pragma unroll
      for (int m = 0; m < 4; ++m) {
        int row = wm * 64 + m * 16 + (lane & 15);
        af[m] = *(const bf16x8*)(A_lds + row * 128 + (koff ^ ((row & 7) << 4)));
      }
#pragma unroll
      for (int n = 0; n < 4; ++n) {
        int row = wn * 64 + n * 16 + (lane & 15);
        bfr[n] = *(const bf16x8*)(B_lds + row * 128 + (koff ^ ((row & 7) << 4)));
      }
#pragma unroll
      for (int m = 0; m < 4; ++m)
#pragma unroll
        for (int n = 0; n < 4; ++n)
          acc[m][n] = __builtin_amdgcn_mfma_f32_16x16x32_bf16(af[m], bfr[n],
                                                              acc[m][n], 0, 0, 0);
    }
    __syncthreads();
  }
  // epilogue: + bias, bf16, scatter to G laid out (T, B, 4H)
  int lr = lane >> 4, lc = lane & 15;
#pragma unroll
  for (int n = 0; n < 4; ++n) {
    int gcol = tile_n * 128 + wn * 64 + n * 16 + lc;
    float bv = bi[gcol];
#pragma unroll
    for (int m = 0; m < 4; ++m) {
      int growb = tile_m * 128 + wm * 64 + m * 16 + lr * 4;
#pragma unroll
      for (int q = 0; q < 4; ++q) {
        int grow = growb + q;                      // = b*256 + t
        float v = acc[m][n][q] + bv;
        size_t gi = ((size_t)(grow & 255) * 64 + (size_t)(grow >> 8)) * 2048 + gcol;
        *(unsigned short*)(Gp + gi * 2) = f2bf(v);
      }
    }
  }
}

// ---------------------------------------------------------------------- K3
// 64 blocks (r = bid>>4 batch-group of 16, c = bid&15 col-group: 32 h-dims,
// cols [i|f|o|g]x32). LDS 161,792 B -> 1 block/CU -> all 64 co-resident.
__global__ __launch_bounds__(256) void k_recur(uint8_t* ws,
                                               const int* __restrict__ vlen,
                                               float* __restrict__ out) {
  extern __shared__ uint8_t smem[];
  uint8_t* Wh_lds = smem;                           // [128][512] bf16 = 131072
  uint8_t* h_lds  = smem + 131072;                  // [16][512]  bf16 = 16384
  float*   tmp    = (float*)(smem + 147456);        // [16][128]  f32  = 8192
  unsigned short* g_lds = (unsigned short*)(smem + 155648);  // [16][128] bf16
  float*   c_lds  = (float*)(smem + 159744);        // [16][32]   f32  = 2048

  int tid = threadIdx.x, bid = blockIdx.x;
  int lane = tid & 63, wave = tid >> 6;
  int r = bid >> 4, c = bid & 15;

  const uint8_t* Gp  = ws + G_OFF;
  const uint8_t* Whr = ws + WHR_OFF;
  uint32_t* hbuf = (uint32_t*)(ws + HBUF_OFF);
  int* slots = (int*)(ws + BAR_OFF);
  int* gen   = (int*)(ws + BAR_OFF + 1024);

  // stage Wh slice once (contiguous, pre-swizzled in global)
  {
    const uint8_t* src = Whr + (size_t)c * 131072;
#pragma unroll
    for (int i = 0; i < 32; ++i) {
      int cb = i * 256 + wave * 64;
      GLOAD_LDS16(src + (size_t)(cb + lane) * 16, Wh_lds + (size_t)cb * 16);
    }
  }
  c_lds[tid] = 0.0f;
  c_lds[tid + 256] = 0.0f;

  int gb_b = tid >> 4;           // local batch 0..15
  int d0 = (tid & 15) << 1;      // dim pair base 0..30
  int gbatch = r * 16 + gb_b;
  int vl = vlen[gbatch];
  float* outH  = out;
  float* outLH = out + 8388608;
  float* outLC = out + 8421376;

  __syncthreads();

  for (int t = 0; t < 256; ++t) {
    uint32_t* hrd = hbuf + (size_t)(t & 1) * 16384;
    uint32_t* hwr = hbuf + (size_t)((t + 1) & 1) * 16384;

    // stage G tile: 16 batches x 128 cols bf16 (4KB), plain loads (const data)
    {
      int bb = tid >> 4, seg = (tid & 15) >> 2, part = tid & 3;
      size_t goff = ((size_t)(t * 64 + r * 16 + bb) * 2048 +
                     (size_t)(seg * 512 + c * 32 + part * 8)) * 2;
      uint4 gv = *(const uint4*)(Gp + goff);
      *(uint4*)((uint8_t*)g_lds + tid * 16) = gv;
    }
    // stage h tile: agent-scope atomic loads (coherent across XCDs)
    {
      uint32_t* hb = hrd + r * 4096;
      uint32_t* hl = (uint32_t*)h_lds;
      uint32_t vb[16];
#pragma unroll
      for (int i = 0; i < 16; ++i)
        vb[i] = __hip_atomic_load(&hb[i * 256 + tid], __ATOMIC_RELAXED,
                                  __HIP_MEMORY_SCOPE_AGENT);
#pragma unroll
      for (int i = 0; i < 16; ++i) hl[i * 256 + tid] = vb[i];
    }
    __syncthreads();

    // MFMA: tmp(16x128) = h(16x512) @ WhSlice(512x128); wave owns tiles 2w,2w+1
    f32x4 acc0 = f32x4{0.f, 0.f, 0.f, 0.f}, acc1 = acc0;
    {
      int lrow = lane & 15;
      int g16 = (lane >> 4) << 4;
      int rb0 = wave * 32 + lrow;
      int rb1 = rb0 + 16;
      int aswz = (lrow & 7) << 4;
      int bswz0 = (rb0 & 7) << 4;
      int bswz1 = (rb1 & 7) << 4;
#pragma unroll
      for (int kk = 0; kk < 16; ++kk) {
        int ko = kk * 64 + g16;
        bf16x8 a  = *(const bf16x8*)(h_lds + lrow * 1024 + (ko ^ aswz));
        bf16x8 b0 = *(const bf16x8*)(Wh_lds + (size_t)rb0 * 1024 + (ko ^ bswz0));
        bf16x8 b1 = *(const bf16x8*)(Wh_lds + (size_t)rb1 * 1024 + (ko ^ bswz1));
        acc0 = __builtin_amdgcn_mfma_f32_16x16x32_bf16(a, b0, acc0, 0, 0, 0);
        acc1 = __builtin_amdgcn_mfma_f32_16x16x32_bf16(a, b1, acc1, 0, 0, 0);
      }
    }
    {  // acc -> tmp (D layout: col=lane&15, row=(lane>>4)*4+q)
      int colb = wave * 32 + (lane & 15);
      int rowd = (lane >> 4) << 2;
#pragma unroll
      for (int q = 0; q < 4; ++q) {
        tmp[(rowd + q) * 128 + colb]      = acc0[q];
        tmp[(rowd + q) * 128 + colb + 16] = acc1[q];
      }
    }
    __syncthreads();

    // gates: thread owns (batch gb_b, dims d0,d0+1)
    {
      float h2[2], c2[2];
#pragma unroll
      for (int u = 0; u < 2; ++u) {
        int dd = d0 + u;
        int tb = gb_b * 128 + dd;
        float ip = tmp[tb]      + bf2f(g_lds[tb]);
        float fp = tmp[tb + 32] + bf2f(g_lds[tb + 32]);
        float op = tmp[tb + 64] + bf2f(g_lds[tb + 64]);
        float gp = tmp[tb + 96] + bf2f(g_lds[tb + 96]);
        float ig = fsigmoid(ip), fg = fsigmoid(fp), og = fsigmoid(op);
        float gt = ftanh(gp);
        float cold = c_lds[gb_b * 32 + dd];
        float cnew = fg * cold + ig * gt;
        c_lds[gb_b * 32 + dd] = cnew;
        h2[u] = og * ftanh(cnew);
        c2[u] = cnew;
      }
      size_t ob = ((size_t)gbatch * 256 + (size_t)t) * 512 + (size_t)(c * 32 + d0);
      float2 hv; hv.x = h2[0]; hv.y = h2[1];
      *(float2*)(outH + ob) = hv;
      if (t == vl - 1) {
        size_t lb = (size_t)gbatch * 512 + (size_t)(c * 32 + d0);
        float2 cv; cv.x = c2[0]; cv.y = c2[1];
        *(float2*)(outLH + lb) = hv;
        *(float2*)(outLC + lb) = cv;
      }
      // publish h pair (pre-swizzled for next step's linear LDS copy)
      uint32_t pk = (uint32_t)f2bf(h2[0]) | ((uint32_t)f2bf(h2[1]) << 16);
      int sd = (c * 32 + d0) ^ ((gb_b & 7) << 3);
      __hip_atomic_store(&hwr[((size_t)gbatch * 512 + (size_t)sd) >> 1], pk,
                         __ATOMIC_RELAXED, __HIP_MEMORY_SCOPE_AGENT);
    }

    if (t < 255) {  // grid barrier: monotonic slots + gen, agent atomics
      __syncthreads();  // drains all waves' vmcnt (h stores at coherent point)
      if (tid == 0)
        __hip_atomic_store(&slots[bid], t + 1, __ATOMIC_RELEASE,
                           __HIP_MEMORY_SCOPE_AGENT);
      if (bid == 0) {
        if (tid < 64) {
          while (__hip_atomic_load(&slots[tid], __ATOMIC_ACQUIRE,
                                   __HIP_MEMORY_SCOPE_AGENT) < t + 1)
            __builtin_amdgcn_s_sleep(1);
        }
        __syncthreads();
        if (tid == 0)
          __hip_atomic_store(gen, t + 1, __ATOMIC_RELEASE,
                             __HIP_MEMORY_SCOPE_AGENT);
      } else {
        if (tid == 0) {
          while (__hip_atomic_load(gen, __ATOMIC_ACQUIRE,
                                   __HIP_MEMORY_SCOPE_AGENT) < t + 1)
            __builtin_amdgcn_s_sleep(1);
        }
        __syncthreads();
      }
    }
  }
}

// ---------------------------------------------------------------------------
extern "C" void kernel_launch(void* const* d_in, const int* in_sizes, int n_in,
                              void* d_out, int out_size, void* d_ws, size_t ws_size,
                              hipStream_t stream) {
  const int*   loc     = (const int*)d_in[0];
  const int*   tdu     = (const int*)d_in[1];
  const int*   tdl     = (const int*)d_in[2];
  const int*   sdu     = (const int*)d_in[3];
  const int*   sdl     = (const int*)d_in[4];
  const int*   vlen    = (const int*)d_in[5];
  const float* loc_emb = (const float*)d_in[6];
  const float* tup     = (const float*)d_in[7];
  const float* tlo     = (const float*)d_in[8];
  const float* sup     = (const float*)d_in[9];
  const float* slo     = (const float*)d_in[10];
  const float* Wt      = (const float*)d_in[11];
  const float* Ws      = (const float*)d_in[12];
  const float* Wi      = (const float*)d_in[13];
  const float* bi      = (const float*)d_in[14];
  const float* Wh      = (const float*)d_in[15];
  uint8_t* ws = (uint8_t*)d_ws;
  float* out = (float*)d_out;

  if (ws_size < WS_NEED) return;  // need ~120.1 MiB scratch

  // allow 161,792 B dynamic LDS for k_recur (no-op if already permitted)
  (void)hipFuncSetAttribute((const void*)k_recur,
                            hipFuncAttributeMaxDynamicSharedMemorySize, 161792);

  k_prep  <<<2081, 256, 0, stream>>>(Wi, Wt, Ws, Wh, ws);
  k_gather<<<16384, 192, 0, stream>>>(loc, tdu, tdl, sdu, sdl,
                                      loc_emb, tup, tlo, sup, slo, ws);
  k_gemm  <<<2048, 256, 0, stream>>>(ws, bi);
  k_recur <<<64, 256, 161792, stream>>>(ws, vlen, out);
}

// Round 2
// 1157.741 us; speedup vs baseline: 1.4953x; 1.4953x over previous
//
#include <hip/hip_runtime.h>
#include <stdint.h>

// ---------------------------------------------------------------------------
// ST-LSTM on MI355X.
//  K0 k_prep   : build W_catT (2048x1536 bf16, transposed+XOR-swizzled),
//                Wh_rearr (2048x512 bf16, col-reordered per recurrence block,
//                swizzled), init h ping-pong buffers (tagged f32).
//  K1 k_gather : A_cat (16384x1536 bf16, swizzled) = [x | q/3600 | sp/1000].
//  K2 k_gemm   : G (T,B,4H) bf16 = A_cat @ W_cat + bi.
//  K3 k_recur  : 64 persistent blocks (4 batch-groups x 16 col-groups),
//                Wh slice resident in LDS. NO barrier: h published as f32
//                words with generation parity in mantissa bit0; readers poll
//                the data itself via relaxed agent-scope u64 loads. One IC
//                round trip per step. WAR-safe by induction (a block writes
//                h_{t+1} only after validating all of h_t; publishing h_t
//                data-depends on having consumed h_{t-1}).
//
// ws layout (bytes), total need = 126,091,264 (~120.2 MiB):
#define A_CAT_OFF  0ull                  // 16384*3072
#define WCT_OFF    50331648ull           // 2048*3072
#define WHR_OFF    56623104ull           // 2048*1024
#define G_OFF      58720256ull           // 16384*2048*2
#define HBUF_OFF   125829120ull          // 2 bufs x 64 batches x 512 f32 (tagged)
#define WS_NEED    126091264ull

typedef short bf16x8 __attribute__((ext_vector_type(8)));
typedef float f32x4  __attribute__((ext_vector_type(4)));

__device__ __forceinline__ unsigned short f2bf(float f) {
  union { float f; uint32_t u; } v; v.f = f;
  uint32_t u = v.u;
  u += 0x7FFFu + ((u >> 16) & 1u);   // RNE
  return (unsigned short)(u >> 16);
}
__device__ __forceinline__ float bf2f(unsigned short h) {
  union { uint32_t u; float f; } v; v.u = ((uint32_t)h) << 16;
  return v.f;
}
__device__ __forceinline__ float u2f(uint32_t u) {
  union { uint32_t u; float f; } v; v.u = u; return v.f;
}
__device__ __forceinline__ uint32_t f2u(float f) {
  union { float f; uint32_t u; } v; v.f = f; return v.u;
}
__device__ __forceinline__ float fsigmoid(float x) { return 1.0f / (1.0f + __expf(-x)); }
__device__ __forceinline__ float ftanh(float x) {
  float e = __expf(2.0f * x);
  return 1.0f - 2.0f / (e + 1.0f);
}
__device__ __forceinline__ uint4 pack8(const unsigned short* v) {
  uint4 r;
  r.x = (uint32_t)v[0] | ((uint32_t)v[1] << 16);
  r.y = (uint32_t)v[2] | ((uint32_t)v[3] << 16);
  r.z = (uint32_t)v[4] | ((uint32_t)v[5] << 16);
  r.w = (uint32_t)v[6] | ((uint32_t)v[7] << 16);
  return r;
}

#define GLOAD_LDS16(GP, LP)                                                   \
  __builtin_amdgcn_global_load_lds(                                          \
      (const __attribute__((address_space(1))) uint32_t*)(GP),               \
      (__attribute__((address_space(3))) uint32_t*)(LP), 16, 0, 0)

// ---------------------------------------------------------------------- K0
__global__ __launch_bounds__(256) void k_prep(
    const float* __restrict__ Wi, const float* __restrict__ Wt,
    const float* __restrict__ Ws, const float* __restrict__ Wh,
    uint8_t* ws) {
  int id = blockIdx.x * 256 + threadIdx.x;
  if (id < 393216) {                       // W_catT: 2048 cols x 192 k-chunks
    int n  = id & 2047;
    int k0 = (id >> 11) << 3;
    unsigned short v[8];
#pragma unroll
    for (int j = 0; j < 8; ++j) {
      int k = k0 + j;
      float x;
      if (k < 512)       x = Wi[k * 2048 + n];
      else if (k < 1024) x = (n < 1536) ? Wt[(k - 512) * 1536 + n] : 0.0f;
      else               x = (n < 1536) ? Ws[(k - 1024) * 1536 + n] : 0.0f;
      v[j] = f2bf(x);
    }
    size_t off = WCT_OFF + (size_t)n * 3072 +
                 (size_t)(((uint32_t)k0 * 2u) ^ (((uint32_t)n & 7u) << 4));
    *(uint4*)(ws + off) = pack8(v);
  } else if (id < 524288) {                // Wh_rearr: 2048 cc x 64 k-chunks
    int id2 = id - 393216;
    int cc  = id2 & 2047;
    int k0  = (id2 >> 11) << 3;
    int col = ((cc >> 5) & 3) * 512 + (cc >> 7) * 32 + (cc & 31);
    unsigned short v[8];
#pragma unroll
    for (int j = 0; j < 8; ++j) v[j] = f2bf(Wh[(size_t)(k0 + j) * 2048 + col]);
    size_t off = WHR_OFF + (size_t)cc * 1024 +
                 (size_t)(((uint32_t)k0 * 2u) ^ (((uint32_t)cc & 7u) << 4));
    *(uint4*)(ws + off) = pack8(v);
  } else if (id < 532480) {                // buf0 = h_0 = +0.0f (tag 0, valid)
    uint4 z; z.x = z.y = z.z = z.w = 0u;
    *(uint4*)(ws + HBUF_OFF + (size_t)(id - 524288) * 16) = z;
  } else {                                 // buf1 = tag 1 (invalid for t=1)
    uint4 z; z.x = z.y = z.z = z.w = 1u;
    *(uint4*)(ws + HBUF_OFF + 131072ull + (size_t)(id - 532480) * 16) = z;
  }
}

// ---------------------------------------------------------------------- K1
__global__ __launch_bounds__(192) void k_gather(
    const int* __restrict__ loc, const int* __restrict__ tdu,
    const int* __restrict__ tdl, const int* __restrict__ sdu,
    const int* __restrict__ sdl,
    const float* __restrict__ loc_emb, const float* __restrict__ tup,
    const float* __restrict__ tlo, const float* __restrict__ sup,
    const float* __restrict__ slo, uint8_t* ws) {
  int m  = blockIdx.x;        // row = b*256 + t
  int t  = m & 255;
  int k0 = threadIdx.x << 3;  // 192 chunks of 8
  float vals[8];
  if (k0 < 512) {
    const float* s = loc_emb + (size_t)loc[m] * 512 + k0;
#pragma unroll
    for (int j = 0; j < 8; ++j) vals[j] = s[j];
  } else if (k0 < 1024) {
    int e = k0 - 512;
    const float* a = tup + (size_t)tdu[m] * 512 + e;
    const float* b = tlo + (size_t)tdl[m] * 512 + e;
    float sc = (t > 0) ? (1.0f / 3600.0f) : 0.0f;
#pragma unroll
    for (int j = 0; j < 8; ++j) vals[j] = (a[j] + b[j]) * sc;
  } else {
    int e = k0 - 1024;
    const float* a = sup + (size_t)sdu[m] * 512 + e;
    const float* b = slo + (size_t)sdl[m] * 512 + e;
    float sc = (t > 0) ? (1.0f / 1000.0f) : 0.0f;
#pragma unroll
    for (int j = 0; j < 8; ++j) vals[j] = (a[j] + b[j]) * sc;
  }
  unsigned short v[8];
#pragma unroll
  for (int j = 0; j < 8; ++j) v[j] = f2bf(vals[j]);
  size_t off = A_CAT_OFF + (size_t)m * 3072 +
               (size_t)(((uint32_t)k0 * 2u) ^ (((uint32_t)m & 7u) << 4));
  *(uint4*)(ws + off) = pack8(v);
}

// ---------------------------------------------------------------------- K2
__global__ __launch_bounds__(256) void k_gemm(uint8_t* ws,
                                              const float* __restrict__ bi) {
  __shared__ uint8_t A_lds[16384];   // 128 rows x 64 k bf16 (swizzled content)
  __shared__ uint8_t B_lds[16384];   // 128 cols x 64 k bf16
  const uint8_t* Acat = ws + A_CAT_OFF;
  const uint8_t* Wct  = ws + WCT_OFF;
  uint8_t* Gp = ws + G_OFF;
  int tid = threadIdx.x;
  int lane = tid & 63, wave = tid >> 6;
  int wm = wave >> 1, wn = wave & 1;
  int tile_m = blockIdx.x >> 4, tile_n = blockIdx.x & 15;

  f32x4 acc[4][4];
#pragma unroll
  for (int m = 0; m < 4; ++m)
#pragma unroll
    for (int n = 0; n < 4; ++n) acc[m][n] = f32x4{0.f, 0.f, 0.f, 0.f};

  for (int kb = 0; kb < 1536; kb += 64) {
#pragma unroll
    for (int i = 0; i < 4; ++i) {
      int lidx = i * 256 + tid;
      int row = lidx >> 3, ch = lidx & 7;
      GLOAD_LDS16(Acat + (size_t)(tile_m * 128 + row) * 3072 + kb * 2 + ch * 16,
                  A_lds + (i * 256 + wave * 64) * 16);
    }
#pragma unroll
    for (int i = 0; i < 4; ++i) {
      int lidx = i * 256 + tid;
      int row = lidx >> 3, ch = lidx & 7;
      GLOAD_LDS16(Wct + (size_t)(tile_n * 128 + row) * 3072 + kb * 2 + ch * 16,
                  B_lds + (i * 256 + wave * 64) * 16);
    }
    __syncthreads();
#pragma unroll
    for (int kk = 0; kk < 2; ++kk) {
      int koff = kk * 64 + ((lane >> 4) << 4);
      bf16x8 af[4], bfr[4];
#pragma unroll
      for (int m = 0; m < 4; ++m) {
        int row = wm * 64 + m * 16 + (lane & 15);
        af[m] = *(const bf16x8*)(A_lds + row * 128 + (koff ^ ((row & 7) << 4)));
      }
#pragma unroll
      for (int n = 0; n < 4; ++n) {
        int row = wn * 64 + n * 16 + (lane & 15);
        bfr[n] = *(const bf16x8*)(B_lds + row * 128 + (koff ^ ((row & 7) << 4)));
      }
#pragma unroll
      for (int m = 0; m < 4; ++m)
#pragma unroll
        for (int n = 0; n < 4; ++n)
          acc[m][n] = __builtin_amdgcn_mfma_f32_16x16x32_bf16(af[m], bfr[n],
                                                              acc[m][n], 0, 0, 0);
    }
    __syncthreads();
  }
  // epilogue: + bias, bf16, scatter to G laid out (T, B, 4H)
  int lr = lane >> 4, lc = lane & 15;
#pragma unroll
  for (int n = 0; n < 4; ++n) {
    int gcol = tile_n * 128 + wn * 64 + n * 16 + lc;
    float bv = bi[gcol];
#pragma unroll
    for (int m = 0; m < 4; ++m) {
      int growb = tile_m * 128 + wm * 64 + m * 16 + lr * 4;
#pragma unroll
      for (int q = 0; q < 4; ++q) {
        int grow = growb + q;                      // = b*256 + t
        float v = acc[m][n][q] + bv;
        size_t gi = ((size_t)(grow & 255) * 64 + (size_t)(grow >> 8)) * 2048 + gcol;
        *(unsigned short*)(Gp + gi * 2) = f2bf(v);
      }
    }
  }
}

// ---------------------------------------------------------------------- K3
// 64 blocks (r = bid>>4 batch-group of 16, c = bid&15 col-group: 32 h-dims,
// cols [i|f|o|g]x32). LDS 155,712 B -> 1 block/CU.
// Per step: G->regs (overlaps poll) ; poll tagged h (1 IC round trip) ;
// cvt->h_lds ; MFMA h@Wh_slice ; gates (c in regs) ; publish tagged h.
__global__ __launch_bounds__(256) void k_recur(uint8_t* ws,
                                               const int* __restrict__ vlen,
                                               float* __restrict__ out) {
  extern __shared__ uint8_t smem[];
  uint8_t* Wh_lds = smem;                           // [128][512] bf16 = 131072
  uint8_t* h_lds  = smem + 131072;                  // [16][512]  bf16 = 16384
  float*   tmp    = (float*)(smem + 147456);        // [16][129]  f32  = 8256

  int tid = threadIdx.x, bid = blockIdx.x;
  int lane = tid & 63, wave = tid >> 6;
  int r = bid >> 4, c = bid & 15;

  const uint8_t* Gp  = ws + G_OFF;
  const uint8_t* Whr = ws + WHR_OFF;

  // stage Wh slice once (contiguous, pre-swizzled in global)
  {
    const uint8_t* src = Whr + (size_t)c * 131072;
#pragma unroll
    for (int i = 0; i < 32; ++i) {
      int cb = i * 256 + wave * 64;
      GLOAD_LDS16(src + (size_t)(cb + lane) * 16, Wh_lds + (size_t)cb * 16);
    }
  }

  int gb_b = tid >> 4;           // local batch 0..15
  int d0 = (tid & 15) << 1;      // dim pair base 0..30
  int gbatch = r * 16 + gb_b;
  int vl = vlen[gbatch];
  float cr0 = 0.0f, cr1 = 0.0f;  // cell state in registers
  float* outH  = out;
  float* outLH = out + 8388608;
  float* outLC = out + 8421376;

  __syncthreads();

  for (int t = 0; t < 256; ++t) {
    // ---- G for this step -> registers (issued first; hides under poll)
    uint32_t gv[4];
    {
      size_t gidx = ((size_t)(t * 64 + gbatch) * 2048 + (size_t)(c * 32 + d0));
#pragma unroll
      for (int g = 0; g < 4; ++g)
        gv[g] = *(const uint32_t*)(Gp + (gidx + (size_t)g * 512) * 2);
    }

    // ---- poll tagged h_t (self-validating data, relaxed agent atomics)
    uint64_t x[16];
    {
      uint64_t* hb64 = (uint64_t*)(ws + HBUF_OFF + (size_t)(t & 1) * 131072 +
                                   (size_t)r * 32768);
      uint32_t expect = (uint32_t)((t >> 1) & 1);
      uint32_t okm = 0;
      while (okm != 0xFFFFu) {
#pragma unroll
        for (int i = 0; i < 16; ++i)
          if (!(okm & (1u << i)))
            x[i] = __hip_atomic_load(&hb64[i * 256 + tid], __ATOMIC_RELAXED,
                                     __HIP_MEMORY_SCOPE_AGENT);
#pragma unroll
        for (int i = 0; i < 16; ++i)
          if (!(okm & (1u << i))) {
            uint32_t lo = (uint32_t)x[i], hi = (uint32_t)(x[i] >> 32);
            if ((((lo ^ expect) & 1u) | ((hi ^ expect) & 1u)) == 0u)
              okm |= (1u << i);
          }
      }
    }
    // ---- convert f32->bf16, write h_lds (iteration i == batch i)
#pragma unroll
    for (int i = 0; i < 16; ++i) {
      uint32_t lo = (uint32_t)x[i], hi = (uint32_t)(x[i] >> 32);
      uint32_t pk = (uint32_t)f2bf(u2f(lo)) | ((uint32_t)f2bf(u2f(hi)) << 16);
      *(uint32_t*)(h_lds + i * 1024 + ((tid * 4) ^ ((i & 7) << 4))) = pk;
    }
    __syncthreads();

    // ---- MFMA: tmp(16x128) = h(16x512) @ WhSlice(512x128)
    f32x4 acc0 = f32x4{0.f, 0.f, 0.f, 0.f}, acc1 = acc0;
    {
      int lrow = lane & 15;
      int g16 = (lane >> 4) << 4;
      int rb0 = wave * 32 + lrow;
      int rb1 = rb0 + 16;
      int aswz = (lrow & 7) << 4;
      int bswz0 = (rb0 & 7) << 4;
      int bswz1 = (rb1 & 7) << 4;
#pragma unroll
      for (int kk = 0; kk < 16; ++kk) {
        int ko = kk * 64 + g16;
        bf16x8 a  = *(const bf16x8*)(h_lds + lrow * 1024 + (ko ^ aswz));
        bf16x8 b0 = *(const bf16x8*)(Wh_lds + (size_t)rb0 * 1024 + (ko ^ bswz0));
        bf16x8 b1 = *(const bf16x8*)(Wh_lds + (size_t)rb1 * 1024 + (ko ^ bswz1));
        acc0 = __builtin_amdgcn_mfma_f32_16x16x32_bf16(a, b0, acc0, 0, 0, 0);
        acc1 = __builtin_amdgcn_mfma_f32_16x16x32_bf16(a, b1, acc1, 0, 0, 0);
      }
    }
    {  // acc -> tmp (D layout: col=lane&15, row(batch)=(lane>>4)*4+q)
      int colb = wave * 32 + (lane & 15);
      int rowd = (lane >> 4) << 2;
#pragma unroll
      for (int q = 0; q < 4; ++q) {
        tmp[(rowd + q) * 129 + colb]      = acc0[q];
        tmp[(rowd + q) * 129 + colb + 16] = acc1[q];
      }
    }
    __syncthreads();

    // ---- gates: thread owns (batch gb_b, dims d0,d0+1); c in registers
    {
      float h2[2], c2[2];
      int tb = gb_b * 129 + d0;
#pragma unroll
      for (int u = 0; u < 2; ++u) {
        float ip = tmp[tb + u]      + bf2f((unsigned short)((gv[0] >> (16 * u)) & 0xFFFF));
        float fp = tmp[tb + u + 32] + bf2f((unsigned short)((gv[1] >> (16 * u)) & 0xFFFF));
        float op = tmp[tb + u + 64] + bf2f((unsigned short)((gv[2] >> (16 * u)) & 0xFFFF));
        float gp = tmp[tb + u + 96] + bf2f((unsigned short)((gv[3] >> (16 * u)) & 0xFFFF));
        float ig = fsigmoid(ip), fg = fsigmoid(fp), og = fsigmoid(op);
        float gt = ftanh(gp);
        float cold = u ? cr1 : cr0;
        float cnew = fg * cold + ig * gt;
        if (u) cr1 = cnew; else cr0 = cnew;
        h2[u] = og * ftanh(cnew);
        c2[u] = cnew;
      }
      // ---- publish tagged h_{t+1} FIRST (critical path for peers)
      {
        uint32_t wtag = (uint32_t)(((t + 1) >> 1) & 1);
        uint32_t w0 = (f2u(h2[0]) & ~1u) | wtag;
        uint32_t w1 = (f2u(h2[1]) & ~1u) | wtag;
        uint64_t pv = (uint64_t)w0 | ((uint64_t)w1 << 32);
        uint64_t* hw64 = (uint64_t*)(ws + HBUF_OFF + (size_t)((t + 1) & 1) * 131072);
        __hip_atomic_store(&hw64[((size_t)gbatch * 512 + (size_t)(c * 32 + d0)) >> 1],
                           pv, __ATOMIC_RELAXED, __HIP_MEMORY_SCOPE_AGENT);
      }
      // ---- outputs (off critical path)
      size_t ob = ((size_t)gbatch * 256 + (size_t)t) * 512 + (size_t)(c * 32 + d0);
      float2 hv; hv.x = h2[0]; hv.y = h2[1];
      *(float2*)(outH + ob) = hv;
      if (t == vl - 1) {
        size_t lb = (size_t)gbatch * 512 + (size_t)(c * 32 + d0);
        float2 cv; cv.x = c2[0]; cv.y = c2[1];
        *(float2*)(outLH + lb) = hv;
        *(float2*)(outLC + lb) = cv;
      }
    }
  }
}

// ---------------------------------------------------------------------------
extern "C" void kernel_launch(void* const* d_in, const int* in_sizes, int n_in,
                              void* d_out, int out_size, void* d_ws, size_t ws_size,
                              hipStream_t stream) {
  const int*   loc     = (const int*)d_in[0];
  const int*   tdu     = (const int*)d_in[1];
  const int*   tdl     = (const int*)d_in[2];
  const int*   sdu     = (const int*)d_in[3];
  const int*   sdl     = (const int*)d_in[4];
  const int*   vlen    = (const int*)d_in[5];
  const float* loc_emb = (const float*)d_in[6];
  const float* tup     = (const float*)d_in[7];
  const float* tlo     = (const float*)d_in[8];
  const float* sup     = (const float*)d_in[9];
  const float* slo     = (const float*)d_in[10];
  const float* Wt      = (const float*)d_in[11];
  const float* Ws      = (const float*)d_in[12];
  const float* Wi      = (const float*)d_in[13];
  const float* bi      = (const float*)d_in[14];
  const float* Wh      = (const float*)d_in[15];
  uint8_t* ws = (uint8_t*)d_ws;
  float* out = (float*)d_out;

  if (ws_size < WS_NEED) return;  // need ~120.2 MiB scratch

  (void)hipFuncSetAttribute((const void*)k_recur,
                            hipFuncAttributeMaxDynamicSharedMemorySize, 155712);

  k_prep  <<<2112, 256, 0, stream>>>(Wi, Wt, Ws, Wh, ws);
  k_gather<<<16384, 192, 0, stream>>>(loc, tdu, tdl, sdu, sdl,
                                      loc_emb, tup, tlo, sup, slo, ws);
  k_gemm  <<<2048, 256, 0, stream>>>(ws, bi);
  k_recur <<<64, 256, 155712, stream>>>(ws, vlen, out);
}